// Round 4
// baseline (77.694 us; speedup 1.0000x reference)
//
#include <hip/hip_runtime.h>
#include <hip/hip_cooperative_groups.h>
#include <math.h>

namespace cg = cooperative_groups;

// Problem constants
#define NPRED 1024
#define NT 64
#define PD 85            // 5 + 80 classes
#define NLOGIT 79        // pred[:, 6:] -> 85-6 columns (reference quirk)
#define ROWS 256         // pred rows per block
#define QBLK 4           // blocks per sample
#define NB 128           // batch (from reference; asserted via in_sizes)

__device__ __forceinline__ float softplusf(float x) {
    return fmaxf(x, 0.0f) + log1pf(expf(-fabsf(x)));
}

// part[] planes (each of size nblk = NB*QBLK):
//  0 sp | 1 cntA 2 bboxA 3 ceA 4 sfmA 5 spmA | 6 cntB 7 bboxB 8 ceB 9 sfmB 10 spmB
// 11 block_max | 12 kv

__global__ __launch_bounds__(256)
void fused_detloss(const float* __restrict__ preds,
                   const float* __restrict__ targets,
                   float* __restrict__ part,
                   float* __restrict__ out,
                   int nb, int nblk)
{
    const int bx  = blockIdx.x;
    const int b   = bx >> 2;
    const int q   = bx & 3;
    const int tid = threadIdx.x;
    const int r   = q * ROWS + tid;          // pred row within sample

    __shared__ float  tgs[NT * 5];
    __shared__ float4 tb[NT];                // x1,y1,x2,y2
    __shared__ float2 tav[NT];               // area, valid(1/0)
    __shared__ float  tcl[NT];
    __shared__ float  red[4][11];
    __shared__ float  redm[4];
    __shared__ float  bmax_s;
    __shared__ int    kv_s;
    __shared__ float  ps[NB];
    __shared__ float  r2[2];

    // ---- issue per-row pred loads early (5 independent dwords) ----
    const float* pp = preds + ((size_t)b * NPRED + r) * PD;
    const float px1 = pp[0], py1 = pp[1], px2 = pp[2], py2 = pp[3], conf = pp[4];

    // ---- stage targets (coalesced float4), pack for the scan ----
    if (tid < (NT * 5 / 4))
        ((float4*)tgs)[tid] = ((const float4*)(targets + (size_t)b * NT * 5))[tid];
    __syncthreads();
    if (tid < NT) {
        float a = tgs[tid*5], c = tgs[tid*5+1], d = tgs[tid*5+2], e = tgs[tid*5+3], f = tgs[tid*5+4];
        tb[tid]  = make_float4(a, c, d, e);
        tav[tid] = make_float2((d - a) * (e - c), (f >= 0.0f) ? 1.0f : 0.0f);
        tcl[tid] = f;
        unsigned long long bl = __ballot(f >= 0.0f);   // wave 0, all 64 lanes active
        if (tid == 0) kv_s = (int)__popcll(bl);
    }
    __syncthreads();

    // ---- per-pred best IoU / first-argmax over 64 targets ----
    const float parea = (px2 - px1) * (py2 - py1);
    float best = -INFINITY;
    int   bidx = 0;
    #pragma unroll 8
    for (int t = 0; t < NT; ++t) {
        const float4 tt = tb[t];
        const float2 av = tav[t];
        float w = fminf(px2, tt.z) - fmaxf(px1, tt.x); w = fmaxf(w, 0.0f);
        float h = fminf(py2, tt.w) - fmaxf(py1, tt.y); h = fmaxf(h, 0.0f);
        float inter = w * h;
        float uni   = parea + av.x - inter;
        float iou   = (av.y != 0.0f) ? inter / (uni + 1e-6f) : -1.0f;
        if (iou > best) { best = iou; bidx = t; }   // strict > => first occurrence (JAX argmax)
    }

    // ---- block max of best ----
    {
        float v = best;
        #pragma unroll
        for (int o = 32; o > 0; o >>= 1) v = fmaxf(v, __shfl_down(v, o));
        if ((tid & 63) == 0) redm[tid >> 6] = v;
        __syncthreads();
        if (tid == 0) bmax_s = fmaxf(fmaxf(redm[0], redm[1]), fmaxf(redm[2], redm[3]));
        __syncthreads();
    }
    const float bmax = bmax_s;
    const bool cA = (best > 0.5f);        // matched_raw
    const bool cB = (best == bmax);       // block-local argmax set (exact equality)

    const float sp = softplusf(conf);
    float vals[11];
    #pragma unroll
    for (int j = 0; j < 11; ++j) vals[j] = 0.0f;
    vals[0] = sp;

    if (cA || cB) {
        const float4 mt = tb[bidx];
        float dd[4] = { px1 - mt.x, py1 - mt.y, px2 - mt.z, py2 - mt.w };
        float bb = 0.0f;
        #pragma unroll
        for (int i = 0; i < 4; ++i) {
            float ad = fabsf(dd[i]);
            bb += (ad < 1.0f) ? 0.5f * dd[i] * dd[i] : ad - 0.5f;
        }
        // online logsumexp over 79 logits (single global pass)
        const float* lg = pp + 6;
        float m = -INFINITY, s = 0.0f;
        #pragma unroll
        for (int i = 0; i < NLOGIT; ++i) {
            float v  = lg[i];
            float nm = fmaxf(m, v);
            s = s * expf(m - nm) + expf(v - nm);
            m = nm;
        }
        const float lse = m + logf(s);
        int label = (int)tcl[bidx];
        label = label < 0 ? 0 : (label > NLOGIT - 1 ? NLOGIT - 1 : label);
        const float cev = lse - pp[6 + label];
        const float sfm = softplusf(-conf);

        if (cA) { vals[1] += 1.0f; vals[2] += bb; vals[3] += cev; vals[4] += sfm; vals[5] += sp; }
        if (cB) { vals[6] += 1.0f; vals[7] += bb; vals[8] += cev; vals[9] += sfm; vals[10] += sp; }
    }

    // ---- block sums of the 11 values ----
    #pragma unroll
    for (int j = 0; j < 11; ++j) {
        float v = vals[j];
        #pragma unroll
        for (int o = 32; o > 0; o >>= 1) v += __shfl_down(v, o);
        if ((tid & 63) == 0) red[tid >> 6][j] = v;
    }
    __syncthreads();
    if (tid < 11)  part[(size_t)tid * nblk + bx] = red[0][tid] + red[1][tid] + red[2][tid] + red[3][tid];
    if (tid == 11) part[(size_t)11  * nblk + bx] = bmax;
    if (tid == 12) part[(size_t)12  * nblk + bx] = (float)kv_s;

    // ================= grid-wide sync, then block 0 finalizes =================
    cg::this_grid().sync();

    if (bx == 0) {
        if (tid < nb) {
            const int s0 = tid * QBLK;
            float bm[QBLK];
            #pragma unroll
            for (int i = 0; i < QBLK; ++i) bm[i] = part[(size_t)11 * nblk + s0 + i];
            float gmax = bm[0];
            #pragma unroll
            for (int i = 1; i < QBLK; ++i) gmax = fmaxf(gmax, bm[i]);

            float sp_total = 0.0f;
            float A[5] = {0,0,0,0,0};     // cnt, bbox, ce, sfm, spm
            float Bv[5] = {0,0,0,0,0};
            #pragma unroll
            for (int i = 0; i < QBLK; ++i) {
                const int idx = s0 + i;
                sp_total += part[(size_t)0 * nblk + idx];
                #pragma unroll
                for (int j = 0; j < 5; ++j) A[j] += part[(size_t)(1 + j) * nblk + idx];
                const float mB = (bm[i] == gmax) ? 1.0f : 0.0f;
                #pragma unroll
                for (int j = 0; j < 5; ++j) Bv[j] += mB * part[(size_t)(6 + j) * nblk + idx];
            }
            const int kv = (int)part[(size_t)12 * nblk + s0];

            const bool  anym = (A[0] > 0.0f);
            const float mcnt = anym ? A[0] : Bv[0];
            const float bboxs= anym ? A[1] : Bv[1];
            const float ces  = anym ? A[2] : Bv[2];
            const float sfms = anym ? A[3] : Bv[3];
            const float spms = anym ? A[4] : Bv[4];
            const float ucnt = (float)NPRED - mcnt;
            const float sfus = sp_total - spms;
            const float bbox_loss = bboxs / fmaxf(mcnt * 4.0f, 1.0f);
            const float cls_loss  = ces   / fmaxf(mcnt, 1.0f);
            const float conf_m    = sfms  / fmaxf(mcnt, 1.0f);
            const float conf_u    = sfus  / fmaxf(ucnt, 1.0f);
            const float conf_loss = (ucnt > 0.0f) ? (conf_m + conf_u) * 0.5f : conf_m;
            const float loss_valid   = bbox_loss + cls_loss + conf_loss;
            const float loss_novalid = sp_total / (float)NPRED;
            ps[tid] = (kv > 0) ? loss_valid : loss_novalid;
        }
        __syncthreads();
        if (tid < NB) {
            float x = (tid < nb) ? ps[tid] : 0.0f;
            #pragma unroll
            for (int o = 32; o > 0; o >>= 1) x += __shfl_down(x, o);
            if ((tid & 63) == 0) r2[tid >> 6] = x;
        }
        __syncthreads();
        if (tid == 0) out[0] = (r2[0] + r2[1]) / (float)nb;
    }
}

extern "C" void kernel_launch(void* const* d_in, const int* in_sizes, int n_in,
                              void* d_out, int out_size, void* d_ws, size_t ws_size,
                              hipStream_t stream) {
    const float* preds   = (const float*)d_in[0];
    const float* targets = (const float*)d_in[1];
    float* out  = (float*)d_out;
    float* part = (float*)d_ws;

    int nb   = in_sizes[0] / (NPRED * PD);   // B = 128
    int nblk = nb * QBLK;                    // 512

    void* args[] = { (void*)&preds, (void*)&targets, (void*)&part,
                     (void*)&out, (void*)&nb, (void*)&nblk };
    hipLaunchCooperativeKernel((void*)fused_detloss, dim3(nblk), dim3(ROWS),
                               args, 0, stream);
}

// Round 5
// 30.626 us; speedup vs baseline: 2.5369x; 2.5369x over previous
//
#include <hip/hip_runtime.h>
#include <math.h>

// Problem constants
#define NPRED 1024
#define NT 64
#define PD 85            // 5 + 80 classes
#define NLOGIT 79        // pred[:, 6:] -> 85-6 columns (reference quirk)
#define QBLK 8           // K1 blocks per sample
#define RPB 128          // pred rows per K1 block
#define THREADS 256      // 2 lanes per row

__device__ __forceinline__ float softplusf(float x) {
    return fmaxf(x, 0.0f) + log1pf(expf(-fabsf(x)));
}

// part[] planes (each of size nblk = NB*QBLK):
//  0 sp | 1 cntA 2 bboxA 3 ceA 4 sfmA 5 spmA | 6 cntB 7 bboxB 8 ceB 9 sfmB 10 spmB
// 11 block_max | 12 kv

__global__ __launch_bounds__(THREADS)
void k1_match(const float* __restrict__ preds,
              const float* __restrict__ targets,
              float* __restrict__ part, int nblk)
{
    const int bx   = blockIdx.x;
    const int b    = bx >> 3;
    const int q    = bx & 7;
    const int tid  = threadIdx.x;
    const int row  = tid >> 1;          // 0..127 within block
    const int half = tid & 1;           // which 32-target half this lane scans
    const int r    = q * RPB + row;     // pred row within sample

    __shared__ float  tgs[NT * 5];
    __shared__ float4 tb[NT];           // x1,y1,x2,y2
    __shared__ float2 tav[NT];          // area, valid
    __shared__ float  tcl[NT];
    __shared__ float  red[4][11];
    __shared__ float  redm[4];
    __shared__ float  bmax_s;
    __shared__ int    kv_s;

    // ---- per-row pred loads (adjacent lanes duplicate -> same cache line) ----
    const float* pp = preds + ((size_t)b * NPRED + r) * PD;
    const float px1 = pp[0], py1 = pp[1], px2 = pp[2], py2 = pp[3], conf = pp[4];

    // ---- stage + pack targets ----
    if (tid < (NT * 5 / 4))
        ((float4*)tgs)[tid] = ((const float4*)(targets + (size_t)b * NT * 5))[tid];
    __syncthreads();
    if (tid < NT) {   // exactly wave 0
        float a = tgs[tid*5], c = tgs[tid*5+1], d = tgs[tid*5+2], e = tgs[tid*5+3], f = tgs[tid*5+4];
        tb[tid]  = make_float4(a, c, d, e);
        tav[tid] = make_float2((d - a) * (e - c), (f >= 0.0f) ? 1.0f : 0.0f);
        tcl[tid] = f;
        unsigned long long bl = __ballot(f >= 0.0f);
        if (tid == 0) kv_s = (int)__popcll(bl);
    }
    __syncthreads();

    // ---- half-scan: lane covers targets [half*32, half*32+32) ----
    const float parea = (px2 - px1) * (py2 - py1);
    const int t0 = half * 32;
    float best = -INFINITY;
    int   bidx = t0;
    #pragma unroll 8
    for (int i = 0; i < 32; ++i) {
        const int t = t0 + i;
        const float4 tt = tb[t];
        const float2 av = tav[t];
        float w = fminf(px2, tt.z) - fmaxf(px1, tt.x); w = fmaxf(w, 0.0f);
        float h = fminf(py2, tt.w) - fmaxf(py1, tt.y); h = fmaxf(h, 0.0f);
        float inter = w * h;
        float uni   = parea + av.x - inter;
        float iou   = (av.y != 0.0f) ? inter / (uni + 1e-6f) : -1.0f;
        if (iou > best) { best = iou; bidx = t; }   // strict > => first occurrence
    }

    // ---- combine the two halves of this row (tie -> lower-index half) ----
    const float obest = __shfl_xor(best, 1);
    const int   obidx = __shfl_xor(bidx, 1);
    const float bA = half ? obest : best;
    const int   iA = half ? obidx : bidx;
    const float bB = half ? best  : obest;
    const int   iB = half ? bidx  : obidx;
    const float fbest = (bA >= bB) ? bA : bB;
    const int   fidx  = (bA >= bB) ? iA : iB;

    // ---- block max of fbest (both lanes of a pair hold the same value) ----
    {
        float v = fbest;
        #pragma unroll
        for (int o = 32; o > 0; o >>= 1) v = fmaxf(v, __shfl_down(v, o));
        if ((tid & 63) == 0) redm[tid >> 6] = v;
        __syncthreads();
        if (tid == 0) bmax_s = fmaxf(fmaxf(redm[0], redm[1]), fmaxf(redm[2], redm[3]));
        __syncthreads();
    }
    const float bmax = bmax_s;
    const bool cA = (fbest > 0.5f);       // matched_raw
    const bool cB = (fbest == bmax);      // block-local argmax set (exact equality)

    const float sp = softplusf(conf);
    float vals[11];
    #pragma unroll
    for (int j = 0; j < 11; ++j) vals[j] = 0.0f;
    if (half == 0) vals[0] = sp;          // one contribution per row

    if (cA || cB) {
        // both lanes of the pair are here together (same fbest/fidx)
        // split the 79-logit online LSE across the pair: 40 + 39
        const float* lg = pp + 6;
        const int base = half * 40;
        const int len  = half ? 39 : 40;
        float m = -INFINITY, s = 0.0f;
        #pragma unroll 8
        for (int i = 0; i < len; ++i) {
            float v  = lg[base + i];
            float nm = fmaxf(m, v);
            s = s * expf(m - nm) + expf(v - nm);
            m = nm;
        }
        const float om = __shfl_xor(m, 1);
        const float os = __shfl_xor(s, 1);
        const float nm = fmaxf(m, om);
        const float st = s * expf(m - nm) + os * expf(om - nm);
        const float lse = nm + logf(st);

        if (half == 0) {
            const float4 mt = tb[fidx];
            float dd[4] = { px1 - mt.x, py1 - mt.y, px2 - mt.z, py2 - mt.w };
            float bb = 0.0f;
            #pragma unroll
            for (int i = 0; i < 4; ++i) {
                float ad = fabsf(dd[i]);
                bb += (ad < 1.0f) ? 0.5f * dd[i] * dd[i] : ad - 0.5f;
            }
            int label = (int)tcl[fidx];
            label = label < 0 ? 0 : (label > NLOGIT - 1 ? NLOGIT - 1 : label);
            const float cev = lse - lg[label];
            const float sfm = softplusf(-conf);

            if (cA) { vals[1] += 1.0f; vals[2] += bb; vals[3] += cev; vals[4] += sfm; vals[5] += sp; }
            if (cB) { vals[6] += 1.0f; vals[7] += bb; vals[8] += cev; vals[9] += sfm; vals[10] += sp; }
        }
    }

    // ---- block sums of the 11 values ----
    #pragma unroll
    for (int j = 0; j < 11; ++j) {
        float v = vals[j];
        #pragma unroll
        for (int o = 32; o > 0; o >>= 1) v += __shfl_down(v, o);
        if ((tid & 63) == 0) red[tid >> 6][j] = v;
    }
    __syncthreads();
    if (tid < 11)  part[(size_t)tid * nblk + bx] = red[0][tid] + red[1][tid] + red[2][tid] + red[3][tid];
    if (tid == 11) part[(size_t)11  * nblk + bx] = bmax;
    if (tid == 12) part[(size_t)12  * nblk + bx] = (float)kv_s;
}

// ------------------------------------------------------------------
// K2: one block of 1024 threads; 8 lanes/sample butterfly combine,
//     per-sample loss, final mean.
// ------------------------------------------------------------------
__global__ __launch_bounds__(1024)
void k2_final(const float* __restrict__ part, float* __restrict__ out,
              int nb, int nblk)
{
    const int t = threadIdx.x;
    const int s = t >> 3, k = t & 7;
    const int bx = s * 8 + k;

    __shared__ float ps[128];
    __shared__ float r2[2];

    float v[13];
    #pragma unroll
    for (int j = 0; j < 13; ++j) v[j] = part[(size_t)j * nblk + bx];

    // gmax over the 8 block maxes of this sample (8-lane butterfly, in-wave)
    float gmax = v[11];
    #pragma unroll
    for (int o = 1; o < 8; o <<= 1) gmax = fmaxf(gmax, __shfl_xor(gmax, o));
    // mask B contributions to blocks whose max equals the global max
    const float mB = (v[11] == gmax) ? 1.0f : 0.0f;
    #pragma unroll
    for (int j = 6; j <= 10; ++j) v[j] *= mB;
    // sum butterflies
    #pragma unroll
    for (int j = 0; j < 11; ++j) {
        #pragma unroll
        for (int o = 1; o < 8; o <<= 1) v[j] += __shfl_xor(v[j], o);
    }

    if (k == 0 && s < nb) {
        const float sp_total = v[0];
        const bool  anym = (v[1] > 0.0f);
        const float mcnt = anym ? v[1] : v[6];
        const float bboxs= anym ? v[2] : v[7];
        const float ces  = anym ? v[3] : v[8];
        const float sfms = anym ? v[4] : v[9];
        const float spms = anym ? v[5] : v[10];
        const float ucnt = (float)NPRED - mcnt;
        const float sfus = sp_total - spms;
        const float bbox_loss = bboxs / fmaxf(mcnt * 4.0f, 1.0f);
        const float cls_loss  = ces   / fmaxf(mcnt, 1.0f);
        const float conf_m    = sfms  / fmaxf(mcnt, 1.0f);
        const float conf_u    = sfus  / fmaxf(ucnt, 1.0f);
        const float conf_loss = (ucnt > 0.0f) ? (conf_m + conf_u) * 0.5f : conf_m;
        const float loss_valid   = bbox_loss + cls_loss + conf_loss;
        const float loss_novalid = sp_total / (float)NPRED;
        const int   kv = (int)v[12];
        ps[s] = (kv > 0) ? loss_valid : loss_novalid;
    }
    __syncthreads();

    if (t < 128) {
        float x = (t < nb) ? ps[t] : 0.0f;
        #pragma unroll
        for (int o = 32; o > 0; o >>= 1) x += __shfl_down(x, o);
        if ((t & 63) == 0) r2[t >> 6] = x;
    }
    __syncthreads();
    if (t == 0) out[0] = (r2[0] + r2[1]) / (float)nb;
}

extern "C" void kernel_launch(void* const* d_in, const int* in_sizes, int n_in,
                              void* d_out, int out_size, void* d_ws, size_t ws_size,
                              hipStream_t stream) {
    const float* preds   = (const float*)d_in[0];
    const float* targets = (const float*)d_in[1];
    float* out  = (float*)d_out;
    float* part = (float*)d_ws;

    const int nb   = in_sizes[0] / (NPRED * PD);   // B = 128
    const int nblk = nb * QBLK;                    // 1024

    hipLaunchKernelGGL(k1_match, dim3(nblk), dim3(THREADS), 0, stream,
                       preds, targets, part, nblk);
    hipLaunchKernelGGL(k2_final, dim3(1), dim3(1024), 0, stream,
                       part, out, nb, nblk);
}